// Round 2
// baseline (191.776 us; speedup 1.0000x reference)
//
#include <hip/hip_runtime.h>
#include <cstdint>

#define NTOK_BLK 64          // tokens per block (one per lane)
#define EMBED    2048
#define NEXP     16
#define WINF     128         // floats per window per token
#define NWIN     (EMBED / WINF)   // 16 windows
#define NTOK_TOTAL (8 * 4096)
#define WOFF     (NTOK_TOTAL * 2) // float offset of indices region in d_out

// global -> LDS async copy, 16B per lane (CK-style addrspace casts)
__device__ __forceinline__ void g2l16(const float* g, float* l) {
    __builtin_amdgcn_global_load_lds(
        (const __attribute__((address_space(1))) void*)(uintptr_t)g,
        (__attribute__((address_space(3))) void*)(uintptr_t)l,
        16, 0, 0);
}

extern "C" __global__ __launch_bounds__(256, 2)
void router_kernel(const float* __restrict__ x,
                   const float* __restrict__ gw,
                   float* __restrict__ out)
{
    // 2 x 32KB double-buffered x tiles: [64 tokens][128 floats], swizzled
    __shared__ float lds[2][NTOK_BLK * WINF];

    const int tid  = threadIdx.x;
    const int lane = tid & 63;
    const int W    = __builtin_amdgcn_readfirstlane(tid >> 6);
    const int t0   = blockIdx.x * NTOK_BLK;

    // LAUNDER the W pointer into a VGPR pair: the compiler can no longer
    // prove the w4 index is wave-uniform, so W loads become per-lane
    // global_load_dwordx4 (64 lanes @ same addr -> 1 coalesced line, L1
    // broadcast) with in-order counted vmcnt -> proper SW pipelining.
    // Round-1 scalarized these to s_load: SMEM is OUT-OF-ORDER, so every
    // dependent use forced lgkmcnt(0) full drains mixed with the ds_reads
    // -> 92% stall. This kills that.
    const float4* gw4 = (const float4*)gw;
    asm("" : "+v"(gw4));

    float acc[NEXP];
#pragma unroll
    for (int e = 0; e < NEXP; ++e) acc[e] = 0.0f;

    // stage one 32KB window into buffer `buf`.
    // LDS is filled LINEARLY in granule order G = it*256 + tid (rule #21);
    // the global SOURCE granule is inverse-swizzled: g = (pos&~7)|((pos^row)&7)
    auto stage = [&](int win, int buf) {
#pragma unroll
        for (int it = 0; it < 8; ++it) {
            const int G   = it * 256 + tid;   // linear granule in tile (16B units)
            const int row = G >> 5;           // local token
            const int pos = G & 31;           // granule slot within row
            const int g   = (pos & ~7) | ((pos ^ row) & 7);
            const float* src = x + (size_t)(t0 + row) * EMBED + win * WINF + g * 4;
            g2l16(src, &lds[buf][G * 4]);
        }
    };

    stage(0, 0);
    __syncthreads();               // drains vmcnt(0): buffer 0 ready

    int cur = 0;
    for (int win = 0; win < NWIN; ++win) {
        if (win + 1 < NWIN) stage(win + 1, cur ^ 1);   // prefetch next window

        const float* buf = lds[cur];
#pragma unroll
        for (int j = 0; j < 8; ++j) {
            const int g   = W * 8 + j;                       // my granule in row
            const int pos = (g & ~7) | ((g ^ lane) & 7);     // swizzled LDS slot
            const float4 x4 = *(const float4*)&buf[lane * WINF + pos * 4];
            const int dbase4 = win * (WINF / 4) + W * 8 + j;
#pragma unroll
            for (int e = 0; e < NEXP; ++e) {
                const float4 w4 = gw4[e * (EMBED / 4) + dbase4];
                acc[e] = fmaf(x4.x, w4.x, acc[e]);
                acc[e] = fmaf(x4.y, w4.y, acc[e]);
                acc[e] = fmaf(x4.z, w4.z, acc[e]);
                acc[e] = fmaf(x4.w, w4.w, acc[e]);
            }
        }
        __syncthreads();           // drains vmcnt+lgkm: next buffer ready, reads done
        cur ^= 1;
    }

    // cross-wave reduction of quarter-dots via LDS (reuse tile memory)
    float* part = (float*)lds;     // [4 waves][64 tokens][16 experts] = 16KB
#pragma unroll
    for (int q = 0; q < 4; ++q) {
        *(float4*)&part[tid * NEXP + q * 4] =
            make_float4(acc[q * 4 + 0], acc[q * 4 + 1], acc[q * 4 + 2], acc[q * 4 + 3]);
    }
    __syncthreads();

    if (W == 0) {
        float tot[NEXP];
#pragma unroll
        for (int e = 0; e < NEXP; ++e) tot[e] = 0.0f;
#pragma unroll
        for (int w = 0; w < 4; ++w) {
#pragma unroll
            for (int q = 0; q < 4; ++q) {
                const float4 p = *(const float4*)&part[(w * 64 + lane) * NEXP + q * 4];
                tot[q * 4 + 0] += p.x;
                tot[q * 4 + 1] += p.y;
                tot[q * 4 + 2] += p.z;
                tot[q * 4 + 3] += p.w;
            }
        }

        // top-2 with lowest-index tie-break (strict >)
        float m1 = tot[0]; int i1 = 0;
#pragma unroll
        for (int e = 1; e < NEXP; ++e) {
            if (tot[e] > m1) { m1 = tot[e]; i1 = e; }
        }
        float m2 = -INFINITY; int i2 = 0;
#pragma unroll
        for (int e = 0; e < NEXP; ++e) {
            const bool sel = (e != i1) && (tot[e] > m2);
            if (sel) { m2 = tot[e]; i2 = e; }
        }

        // normalized top-2 softmax = softmax over the two logits
        const float ed = __expf(m2 - m1);   // <= 1
        const float w1 = 1.0f / (1.0f + ed);
        const float w2 = 1.0f - w1;

        const int t = t0 + lane;
        out[t * 2 + 0] = w1;
        out[t * 2 + 1] = w2;
        out[WOFF + t * 2 + 0] = (float)i1;
        out[WOFF + t * 2 + 1] = (float)i2;
    }
}

extern "C" void kernel_launch(void* const* d_in, const int* in_sizes, int n_in,
                              void* d_out, int out_size, void* d_ws, size_t ws_size,
                              hipStream_t stream) {
    const float* x  = (const float*)d_in[0];   // [8,4096,2048] f32
    const float* gw = (const float*)d_in[1];   // [16,2048] f32
    float* out = (float*)d_out;                // weights[65536] ++ indices-as-f32[65536]

    const int nblocks = NTOK_TOTAL / NTOK_BLK; // 512
    router_kernel<<<dim3(nblocks), dim3(256), 0, stream>>>(x, gw, out);
}

// Round 3
// 102.621 us; speedup vs baseline: 1.8688x; 1.8688x over previous
//
#include <hip/hip_runtime.h>
#include <cstdint>

#define EMBED     2048
#define NEXP      16
#define NWAVES    8                   // d-split waves per block
#define TOKB      64                  // tokens per block (one per lane)
#define NTOK_TOTAL (8 * 4096)
#define WOFF      (NTOK_TOTAL * 2)    // float offset of indices region in d_out
#define DPW       (EMBED / NWAVES)    // 256 floats of d per wave
#define C4        (DPW / 4)           // 64 float4 steps per wave
#define PAD       17                  // LDS row pad: stride-17 dwords -> conflict-free

// Barrier-free direct-load router:
//  - lane = token, wave = d-slice. No LDS, no syncthreads in the main loop.
//  - x: per-lane float4 loads (64-line scatter per instr, but each 64B line is
//    consumed over 4 consecutive c-steps -> L1 amortizes; HBM bytes = x size).
//  - W: wave-uniform indexing -> compiler scalarizes to s_load_dwordx4 (K$
//    broadcast). lgkmcnt has NO ds ops to contend with now, and there is no
//    barrier drain coupling SMEM/VMEM latency across waves.
//  - 512 threads/block, 2 blocks/CU -> 16 waves/CU of fully independent work.
extern "C" __global__ __launch_bounds__(NWAVES * 64, 4)
void router_kernel(const float* __restrict__ x,
                   const float* __restrict__ gw,
                   float* __restrict__ out)
{
    __shared__ float part[NWAVES][TOKB][PAD];   // ~35 KB

    const int tid  = threadIdx.x;
    const int lane = tid & 63;
    const int W    = __builtin_amdgcn_readfirstlane(tid >> 6);
    const int t0   = blockIdx.x * TOKB;

    const float*  xrow = x + (size_t)(t0 + lane) * EMBED + W * DPW;  // per-lane
    const float4* wv   = (const float4*)gw + W * C4;                 // uniform

    float acc[NEXP];
#pragma unroll
    for (int e = 0; e < NEXP; ++e) acc[e] = 0.0f;

#pragma unroll 4
    for (int c = 0; c < C4; ++c) {
        const float4 x4 = *(const float4*)(xrow + c * 4);
#pragma unroll
        for (int e = 0; e < NEXP; ++e) {
            const float4 w4 = wv[e * (EMBED / 4) + c];   // s_load broadcast
            acc[e] = fmaf(x4.x, w4.x, acc[e]);
            acc[e] = fmaf(x4.y, w4.y, acc[e]);
            acc[e] = fmaf(x4.z, w4.z, acc[e]);
            acc[e] = fmaf(x4.w, w4.w, acc[e]);
        }
    }

    // one-shot cross-wave reduction (stride-17 rows: lanes 32 apart share a
    // bank -> 2-way, free)
#pragma unroll
    for (int e = 0; e < NEXP; ++e) part[W][lane][e] = acc[e];
    __syncthreads();

    if (tid < TOKB) {               // wave 0 only: uniform branch
        float tot[NEXP];
#pragma unroll
        for (int e = 0; e < NEXP; ++e) tot[e] = 0.0f;
#pragma unroll
        for (int w = 0; w < NWAVES; ++w) {
#pragma unroll
            for (int e = 0; e < NEXP; ++e) tot[e] += part[w][tid][e];
        }

        // top-2 with lowest-index tie-break (strict >)
        float m1 = tot[0]; int i1 = 0;
#pragma unroll
        for (int e = 1; e < NEXP; ++e) {
            if (tot[e] > m1) { m1 = tot[e]; i1 = e; }
        }
        float m2 = -INFINITY; int i2 = 0;
#pragma unroll
        for (int e = 0; e < NEXP; ++e) {
            const bool sel = (e != i1) && (tot[e] > m2);
            if (sel) { m2 = tot[e]; i2 = e; }
        }

        // normalized top-2 weights = softmax over the two logits
        const float ed = __expf(m2 - m1);   // <= 1
        const float w1 = 1.0f / (1.0f + ed);
        const float w2 = 1.0f - w1;

        const int t = t0 + tid;
        out[t * 2 + 0] = w1;
        out[t * 2 + 1] = w2;
        out[WOFF + t * 2 + 0] = (float)i1;
        out[WOFF + t * 2 + 1] = (float)i2;
    }
}

extern "C" void kernel_launch(void* const* d_in, const int* in_sizes, int n_in,
                              void* d_out, int out_size, void* d_ws, size_t ws_size,
                              hipStream_t stream) {
    const float* x  = (const float*)d_in[0];   // [8,4096,2048] f32
    const float* gw = (const float*)d_in[1];   // [16,2048] f32
    float* out = (float*)d_out;                // weights[65536] ++ indices-as-f32[65536]

    const int nblocks = NTOK_TOTAL / TOKB;     // 512 blocks x 512 threads
    router_kernel<<<dim3(nblocks), dim3(NWAVES * 64), 0, stream>>>(x, gw, out);
}

// Round 4
// 59.766 us; speedup vs baseline: 3.2088x; 1.7170x over previous
//
#include <hip/hip_runtime.h>
#include <cstdint>

#define EMBED      2048
#define NEXP       16
#define NWAVES     8                    // d-split waves per block
#define TOKB       64                   // tokens per block (one per lane)
#define WINF       128                  // floats per window per token
#define NWIN       (EMBED / WINF)       // 16 windows
#define NTOK_TOTAL (8 * 4096)
#define WOFF       (NTOK_TOTAL * 2)     // float offset of indices region in d_out
#define PAD        17                   // epilogue LDS row pad

// global -> LDS async copy, 16B per lane
__device__ __forceinline__ void g2l16(const float* g, float* l) {
    __builtin_amdgcn_global_load_lds(
        (const __attribute__((address_space(1))) void*)(uintptr_t)g,
        (__attribute__((address_space(3))) void*)(uintptr_t)l,
        16, 0, 0);
}

// Windowed LDS staging for BOTH x and W:
//  - x: coalesced gload_lds (inverse-swizzled source, linear dest — rule #21),
//    read per-lane (lane = token) via swizzled ds_read_b128.
//  - W: 8 KB/window staged by 1 gload_lds/thread, read at WAVE-UNIFORM
//    addresses -> LDS broadcast (conflict-free). Zero s_load / zero VMEM in
//    the compute loop: lgkmcnt carries only in-order ds_reads, vmcnt only the
//    next window's prefetch, drained once per window at the barrier.
//  - 512 thr/block (8 d-split waves, DPW=256), 80 KB LDS -> 2 blocks/CU
//    = 16 waves/CU.
extern "C" __global__ __launch_bounds__(NWAVES * 64, 4)
void router_kernel(const float* __restrict__ x,
                   const float* __restrict__ gw,
                   float* __restrict__ out)
{
    __shared__ float lds_x[2][TOKB * WINF];   // 2 x 32 KB
    __shared__ float lds_w[2][NEXP * WINF];   // 2 x  8 KB

    const int tid  = threadIdx.x;
    const int lane = tid & 63;
    const int W    = __builtin_amdgcn_readfirstlane(tid >> 6);
    const int t0   = blockIdx.x * TOKB;

    float acc[NEXP];
#pragma unroll
    for (int e = 0; e < NEXP; ++e) acc[e] = 0.0f;

    // stage one x window (32 KB): 2048 granules, 4 per thread.
    // LDS filled LINEARLY at granule G; global source granule is
    // inverse-swizzled: gsrc = (pos&~7)|((pos^row)&7)   (R1-proven involution)
    auto stage_x = [&](int win, int buf) {
#pragma unroll
        for (int it = 0; it < 4; ++it) {
            const int G   = it * 512 + tid;   // granule in tile (16B units)
            const int row = G >> 5;           // local token
            const int pos = G & 31;           // slot within row (32 granules)
            const int g   = (pos & ~7) | ((pos ^ row) & 7);
            const float* src = x + (size_t)(t0 + row) * EMBED + win * WINF + g * 4;
            g2l16(src, &lds_x[buf][G * 4]);
        }
    };

    // stage one W window (8 KB): 512 granules, 1 per thread; layout
    // [e][WINF floats], linear (uniform broadcast reads -> no swizzle needed)
    auto stage_w = [&](int win, int buf) {
        const int e  = tid >> 5;              // 0..15
        const int wg = tid & 31;              // granule within window row
        const float* src = gw + e * EMBED + win * WINF + wg * 4;
        g2l16(src, &lds_w[buf][tid * 4]);
    };

    stage_x(0, 0);
    stage_w(0, 0);
    __syncthreads();                // drains vmcnt(0): buffer 0 ready

    int cur = 0;
    for (int win = 0; win < NWIN; ++win) {
        if (win + 1 < NWIN) {       // prefetch next window
            stage_x(win + 1, cur ^ 1);
            stage_w(win + 1, cur ^ 1);
        }

        const float* bx = lds_x[cur];
        const float* bw = lds_w[cur];
#pragma unroll
        for (int j = 0; j < 4; ++j) {
            const int g   = W * 4 + j;                       // my granule in window
            const int pos = (g & ~7) | ((g ^ lane) & 7);     // swizzled x slot
            const float4 x4 = *(const float4*)&bx[lane * WINF + pos * 4];
#pragma unroll
            for (int e = 0; e < NEXP; ++e) {
                const float4 w4 = *(const float4*)&bw[e * WINF + g * 4]; // broadcast
                acc[e] = fmaf(x4.x, w4.x, acc[e]);
                acc[e] = fmaf(x4.y, w4.y, acc[e]);
                acc[e] = fmaf(x4.z, w4.z, acc[e]);
                acc[e] = fmaf(x4.w, w4.w, acc[e]);
            }
        }
        __syncthreads();            // next buffer staged, this buffer's reads done
        cur ^= 1;
    }

    // cross-wave reduction (overlay scratch on lds_x; stride-17 rows)
    float (*part)[TOKB][PAD] = (float (*)[TOKB][PAD])lds_x;
#pragma unroll
    for (int e = 0; e < NEXP; ++e) part[W][lane][e] = acc[e];
    __syncthreads();

    if (tid < TOKB) {               // wave 0 only: uniform branch
        float tot[NEXP];
#pragma unroll
        for (int e = 0; e < NEXP; ++e) tot[e] = 0.0f;
#pragma unroll
        for (int w = 0; w < NWAVES; ++w) {
#pragma unroll
            for (int e = 0; e < NEXP; ++e) tot[e] += part[w][tid][e];
        }

        // top-2 with lowest-index tie-break (strict >)
        float m1 = tot[0]; int i1 = 0;
#pragma unroll
        for (int e = 1; e < NEXP; ++e) {
            if (tot[e] > m1) { m1 = tot[e]; i1 = e; }
        }
        float m2 = -INFINITY; int i2 = 0;
#pragma unroll
        for (int e = 0; e < NEXP; ++e) {
            const bool sel = (e != i1) && (tot[e] > m2);
            if (sel) { m2 = tot[e]; i2 = e; }
        }

        // normalized top-2 weights = softmax over the two logits
        const float ed = __expf(m2 - m1);   // <= 1
        const float w1 = 1.0f / (1.0f + ed);
        const float w2 = 1.0f - w1;

        const int t = t0 + tid;
        out[t * 2 + 0] = w1;
        out[t * 2 + 1] = w2;
        out[WOFF + t * 2 + 0] = (float)i1;
        out[WOFF + t * 2 + 1] = (float)i2;
    }
}

extern "C" void kernel_launch(void* const* d_in, const int* in_sizes, int n_in,
                              void* d_out, int out_size, void* d_ws, size_t ws_size,
                              hipStream_t stream) {
    const float* x  = (const float*)d_in[0];   // [8,4096,2048] f32
    const float* gw = (const float*)d_in[1];   // [16,2048] f32
    float* out = (float*)d_out;                // weights[65536] ++ indices-as-f32[65536]

    const int nblocks = NTOK_TOTAL / TOKB;     // 512 blocks x 512 threads
    router_kernel<<<dim3(nblocks), dim3(NWAVES * 64), 0, stream>>>(x, gw, out);
}